// Round 4
// baseline (6161.800 us; speedup 1.0000x reference)
//
#include <hip/hip_runtime.h>
#include <hip/hip_bf16.h>
#include <stdint.h>

typedef unsigned short u16;
typedef unsigned int   u32;
typedef unsigned long long ull;
typedef __attribute__((ext_vector_type(8))) short short8;
typedef __attribute__((ext_vector_type(4))) float f32x4;
typedef __attribute__((ext_vector_type(16))) float f32x16;

#define T_OUT 36
#define NB    256
#define S_IN  96
#define DD    1024
#define HH    1024

#define OFF_HID  9437184
#define OFF_ATTN 9961472

enum { EPI_F32 = 0, EPI_COMB = 1, EPI_BF16 = 2, EPI_YOUT = 3 };

__device__ __forceinline__ float b2f(u16 u) {
    return __uint_as_float(((u32)u) << 16);
}
__device__ __forceinline__ u16 f2b(float f) {
    __hip_bfloat16 h = __float2bfloat16(f);
    return __builtin_bit_cast(unsigned short, h);
}

template <int RAW>
__device__ __forceinline__ short8 ld8(const void* p, size_t eoff, bool isbf) {
    if (RAW == 0 || isbf) {
        return *(const short8*)((const u16*)p + eoff);
    } else {
        const float* f = (const float*)p + eoff;
        short8 r;
        #pragma unroll
        for (int i = 0; i < 8; ++i) r[i] = (short)f2b(f[i]);
        return r;
    }
}

// dtype detector: flag=1 -> bf16 inputs, 0 -> f32 inputs.
__global__ __launch_bounds__(256) void k_detect(const u32* __restrict__ t,
                                                int* __restrict__ flag)
{
    __shared__ int cnt[256];
    u32 w = t[threadIdx.x];
    int e = (w >> 7) & 0xFF;               // exponent of low-half-as-bf16
    cnt[threadIdx.x] = (e >= 100 && e <= 140) ? 1 : 0;
    __syncthreads();
    for (int s = 128; s > 0; s >>= 1) {
        if (threadIdx.x < s) cnt[threadIdx.x] += cnt[threadIdx.x + s];
        __syncthreads();
    }
    if (threadIdx.x == 0) flag[0] = (cnt[0] >= 128) ? 1 : 0;
}

__global__ __launch_bounds__(256) void k_cvt16(const void* __restrict__ src,
                                               u16* __restrict__ dst, int n4,
                                               const int* __restrict__ flagp)
{
    const int i = blockIdx.x * 256 + threadIdx.x;
    if (i >= n4) return;
    if (*flagp) {
        ((ull*)dst)[i] = ((const ull*)src)[i];
    } else {
        f32x4 v = ((const f32x4*)src)[i];
        ull pk = (ull)f2b(v[0]) | ((ull)f2b(v[1]) << 16)
               | ((ull)f2b(v[2]) << 32) | ((ull)f2b(v[3]) << 48);
        ((ull*)dst)[i] = pk;
    }
}

__global__ __launch_bounds__(256) void k_cvtf(const void* __restrict__ src,
                                              float* __restrict__ dst, int n,
                                              const int* __restrict__ flagp)
{
    const int i = blockIdx.x * 256 + threadIdx.x;
    if (i >= n) return;
    dst[i] = *flagp ? b2f(((const u16*)src)[i]) : ((const float*)src)[i];
}

__global__ __launch_bounds__(256) void k_trcvt(const void* __restrict__ in,
                                               u16* __restrict__ out,
                                               const int* __restrict__ flagp)
{
    const bool isbf = (*flagp != 0);
    __shared__ u16 tile[64][65];
    const int bx = blockIdx.x * 64, by = blockIdx.y * 64;
    const int c = threadIdx.x & 63, r0 = threadIdx.x >> 6;
    #pragma unroll
    for (int rr = 0; rr < 16; ++rr) {
        int r = r0 * 16 + rr;
        size_t idx = (size_t)(by + r) * 1024 + bx + c;
        tile[r][c] = isbf ? ((const u16*)in)[idx] : f2b(((const float*)in)[idx]);
    }
    __syncthreads();
    #pragma unroll
    for (int rr = 0; rr < 16; ++rr) {
        int r = r0 * 16 + rr;
        out[(size_t)(bx + r) * 1024 + by + c] = tile[c][r];
    }
}

__global__ __launch_bounds__(256) void k_bc(const void* __restrict__ W2,
                                            const void* __restrict__ b1,
                                            const void* __restrict__ b2,
                                            float* __restrict__ bc,
                                            const int* __restrict__ flagp)
{
    const bool isbf = (*flagp != 0);
    const int d = blockIdx.x * 256 + threadIdx.x;
    float s = isbf ? b2f(((const u16*)b2)[d]) : ((const float*)b2)[d];
    if (isbf) {
        const u16* wr = (const u16*)W2 + (size_t)d * 1024;
        const u16* bb = (const u16*)b1;
        for (int j = 0; j < 1024; ++j) s += b2f(wr[j]) * b2f(bb[j]);
    } else {
        const float* wr = (const float*)W2 + (size_t)d * 1024;
        const float* bb = (const float*)b1;
        for (int j = 0; j < 1024; ++j) s += wr[j] * bb[j];
    }
    bc[d] = s;
}

template <int EPI, int RAWA, int RAWB>
__global__ __launch_bounds__(128) void k_gemm(
    const void* __restrict__ A0, const void* __restrict__ B0, void* __restrict__ C0,
    const void* __restrict__ A1, const void* __restrict__ B1, void* __restrict__ C1,
    int lda, int ldb, int M, int N, int K, size_t b_eoff,
    const float* __restrict__ fbias, int t, int ldc,
    const int* __restrict__ flagp)
{
    const bool isbf = (*flagp != 0);
    const void* A = A0; const void* B = B0; void* Cp = C0;
    if (blockIdx.z) { A = A1; B = B1; Cp = C1; }

    __shared__ short8 As[64 * 4];
    __shared__ short8 Bs[128 * 4];

    const int tid  = threadIdx.x;
    const int lane = tid & 63;
    const int w    = tid >> 6;
    const int bm   = blockIdx.x * 64;
    const int bn   = blockIdx.y * 128;

    const int srow = tid >> 2;
    const int sg   = tid & 3;
    const int m0   = lane & 31;
    const int kq   = lane >> 5;

    f32x16 acc[2][2];
    #pragma unroll
    for (int i = 0; i < 2; ++i)
        #pragma unroll
        for (int j = 0; j < 2; ++j) acc[i][j] = (f32x16)0.0f;

    const int kiter = K >> 5;
    for (int kt = 0; kt < kiter; ++kt) {
        const int k0 = kt << 5;
        short8 av[2], bv[4];
        #pragma unroll
        for (int i = 0; i < 2; ++i) {
            int r = srow + 32 * i;
            av[i] = ld8<RAWA>(A, (size_t)(bm + r) * lda + k0 + sg * 8, isbf);
        }
        #pragma unroll
        for (int i = 0; i < 4; ++i) {
            int gr = bn + srow + 32 * i;
            if (gr < N) bv[i] = ld8<RAWB>(B, b_eoff + (size_t)gr * ldb + k0 + sg * 8, isbf);
            else        bv[i] = (short8)(short)0;
        }
        __syncthreads();
        #pragma unroll
        for (int i = 0; i < 2; ++i) {
            int r = srow + 32 * i;
            As[r * 4 + (sg ^ (r & 3))] = av[i];
        }
        #pragma unroll
        for (int i = 0; i < 4; ++i) {
            int r = srow + 32 * i;
            Bs[r * 4 + (sg ^ (r & 3))] = bv[i];
        }
        __syncthreads();
        #pragma unroll
        for (int ks = 0; ks < 2; ++ks) {
            const int gk = ks * 2 + kq;
            short8 af[2], bf[2];
            #pragma unroll
            for (int i = 0; i < 2; ++i) {
                int r = i * 32 + m0;
                af[i] = As[r * 4 + (gk ^ (r & 3))];
            }
            #pragma unroll
            for (int j = 0; j < 2; ++j) {
                int r = w * 64 + j * 32 + m0;
                bf[j] = Bs[r * 4 + (gk ^ (r & 3))];
            }
            #pragma unroll
            for (int i = 0; i < 2; ++i)
                #pragma unroll
                for (int j = 0; j < 2; ++j)
                    acc[i][j] = __builtin_amdgcn_mfma_f32_32x32x16_bf16(
                        af[i], bf[j], acc[i][j], 0, 0, 0);
        }
    }

    #pragma unroll
    for (int i = 0; i < 2; ++i) {
        #pragma unroll
        for (int j = 0; j < 2; ++j) {
            #pragma unroll
            for (int reg = 0; reg < 16; ++reg) {
                int row = (reg & 3) + 8 * (reg >> 2) + 4 * kq;
                int gr = bm + i * 32 + row;
                int gc = bn + w * 64 + j * 32 + m0;
                if (gc < N) {
                    float v = acc[i][j][reg];
                    if constexpr (EPI == EPI_F32) {
                        ((float*)Cp)[(size_t)gr * ldc + gc] = v;
                    } else if constexpr (EPI == EPI_COMB) {
                        v += fbias[gc];
                        v = fmaxf(v, 0.0f);
                        ((u16*)Cp)[(size_t)gr * ldc + gc] = f2b(v);
                    } else if constexpr (EPI == EPI_BF16) {
                        ((u16*)Cp)[(size_t)gr * ldc + gc] = f2b(v);
                    } else {
                        v += fbias[gc];
                        size_t oidx = (size_t)gr * (T_OUT * DD) + (size_t)t * DD + gc;
                        if (isbf) ((u16*)Cp)[oidx] = f2b(v);
                        else      ((float*)Cp)[oidx] = v;
                    }
                }
            }
        }
    }
}

__global__ __launch_bounds__(256) void k_attn(
    const u16* __restrict__ hb, const u16* __restrict__ attnWB,
    const float* __restrict__ attnBF, const void* __restrict__ enc,
    const void* __restrict__ target, u16* __restrict__ xcat,
    void* __restrict__ d_out, const int* __restrict__ flagp, int t)
{
    const bool isbf = (*flagp != 0);
    __shared__ float cbuf[2048];
    __shared__ float sc[S_IN];
    __shared__ float red[2];
    const int b = blockIdx.x, tid = threadIdx.x;

    float x0, x1, x2, x3;
    const size_t xoff = ((size_t)b * T_OUT + t) * DD + (size_t)tid * 4;
    if (isbf) {
        ull xv = *(const ull*)((const u16*)target + xoff);
        x0 = b2f((u16)(xv & 0xffff));
        x1 = b2f((u16)((xv >> 16) & 0xffff));
        x2 = b2f((u16)((xv >> 32) & 0xffff));
        x3 = b2f((u16)(xv >> 48));
    } else {
        f32x4 v = *(const f32x4*)((const float*)target + xoff);
        x0 = v[0]; x1 = v[1]; x2 = v[2]; x3 = v[3];
    }
    cbuf[tid * 4 + 0] = x0; cbuf[tid * 4 + 1] = x1;
    cbuf[tid * 4 + 2] = x2; cbuf[tid * 4 + 3] = x3;
    ull pk = (ull)f2b(x0) | ((ull)f2b(x1) << 16)
           | ((ull)f2b(x2) << 32) | ((ull)f2b(x3) << 48);
    ((ull*)(xcat + (size_t)b * 2048))[tid] = pk;

    ull hv = ((const ull*)(hb + (size_t)(NB + b) * HH))[tid];
    cbuf[1024 + tid * 4 + 0] = b2f((u16)(hv & 0xffff));
    cbuf[1024 + tid * 4 + 1] = b2f((u16)((hv >> 16) & 0xffff));
    cbuf[1024 + tid * 4 + 2] = b2f((u16)((hv >> 32) & 0xffff));
    cbuf[1024 + tid * 4 + 3] = b2f((u16)(hv >> 48));
    __syncthreads();

    if (tid < S_IN) {
        const u16* wr = attnWB + (size_t)tid * 2048;
        float acc = attnBF[tid];
        for (int k = 0; k < 2048; k += 8) {
            short8 v = *(const short8*)(wr + k);
            #pragma unroll
            for (int j = 0; j < 8; ++j) acc += cbuf[k + j] * b2f((u16)v[j]);
        }
        sc[tid] = acc;
    }
    __syncthreads();
    if (tid == 0) {
        float m = -1e30f;
        for (int s = 0; s < S_IN; ++s) m = fmaxf(m, sc[s]);
        red[0] = m;
    }
    __syncthreads();
    if (tid < S_IN) sc[tid] = expf(sc[tid] - red[0]);
    __syncthreads();
    if (tid == 0) {
        float s = 0.f;
        for (int i = 0; i < S_IN; ++i) s += sc[i];
        red[1] = 1.0f / s;
    }
    __syncthreads();
    if (tid < S_IN) {
        float a = sc[tid] * red[1];
        sc[tid] = a;
        size_t aidx = OFF_ATTN + (size_t)b * T_OUT * S_IN + (size_t)t * S_IN + tid;
        if (isbf) ((u16*)d_out)[aidx] = f2b(a);
        else      ((float*)d_out)[aidx] = a;
    }
    __syncthreads();

    float a0 = 0.f, a1 = 0.f, a2 = 0.f, a3 = 0.f;
    if (isbf) {
        const u16* eb = (const u16*)enc + (size_t)b * S_IN * HH + (size_t)tid * 4;
        for (int s = 0; s < S_IN; ++s) {
            float aw = sc[s];
            ull v = *(const ull*)(eb + (size_t)s * HH);
            a0 += aw * b2f((u16)(v & 0xffff));
            a1 += aw * b2f((u16)((v >> 16) & 0xffff));
            a2 += aw * b2f((u16)((v >> 32) & 0xffff));
            a3 += aw * b2f((u16)(v >> 48));
        }
    } else {
        const float* eb = (const float*)enc + (size_t)b * S_IN * HH + (size_t)tid * 4;
        for (int s = 0; s < S_IN; ++s) {
            float aw = sc[s];
            f32x4 v = *(const f32x4*)(eb + (size_t)s * HH);
            a0 += aw * v[0]; a1 += aw * v[1]; a2 += aw * v[2]; a3 += aw * v[3];
        }
    }
    ull wk = (ull)f2b(a0) | ((ull)f2b(a1) << 16)
           | ((ull)f2b(a2) << 32) | ((ull)f2b(a3) << 48);
    *(ull*)(xcat + (size_t)b * 2048 + 1024 + (size_t)tid * 4) = wk;
}

__global__ __launch_bounds__(256) void k_gate(
    const float* __restrict__ gi, const float* __restrict__ gh,
    const float* __restrict__ bihF, const float* __restrict__ bhhF,
    float* __restrict__ hf, u16* __restrict__ hb)
{
    const int idx = blockIdx.x * 256 + threadIdx.x;
    const int b = idx >> 10, j = idx & 1023;
    const size_t r3 = (size_t)b * 3072;
    float ir  = gi[r3 + j]        + bihF[j];
    float iz  = gi[r3 + 1024 + j] + bihF[1024 + j];
    float in_ = gi[r3 + 2048 + j] + bihF[2048 + j];
    float hr  = gh[r3 + j]        + bhhF[j];
    float hz  = gh[r3 + 1024 + j] + bhhF[1024 + j];
    float hn  = gh[r3 + 2048 + j] + bhhF[2048 + j];
    float r = 1.f / (1.f + expf(-(ir + hr)));
    float z = 1.f / (1.f + expf(-(iz + hz)));
    float n = tanhf(in_ + r * hn);
    float hold = hf ? hf[idx] : b2f(hb[idx]);
    float hnew = (1.f - z) * n + z * hold;
    if (hf) hf[idx] = hnew;
    hb[idx] = f2b(hnew);
}

__global__ __launch_bounds__(256) void k_init(const void* __restrict__ hid,
                                              float* __restrict__ hf,
                                              u16* __restrict__ hb,
                                              const int* __restrict__ flagp)
{
    const int i = blockIdx.x * 256 + threadIdx.x;
    float v = *flagp ? b2f(((const u16*)hid)[i]) : ((const float*)hid)[i];
    if (hf) hf[i] = v;
    hb[i] = f2b(v);
}

__global__ __launch_bounds__(256) void k_hidout(const float* __restrict__ hf,
                                                const u16* __restrict__ hb,
                                                void* __restrict__ d_out,
                                                const int* __restrict__ flagp)
{
    const int i = blockIdx.x * 256 + threadIdx.x;
    float v = hf ? hf[i] : b2f(hb[i]);
    if (*flagp) ((u16*)d_out)[OFF_HID + i] = f2b(v);
    else        ((float*)d_out)[OFF_HID + i] = v;
}

extern "C" void kernel_launch(void* const* d_in, const int* in_sizes, int n_in,
                              void* d_out, int out_size, void* d_ws, size_t ws_size,
                              hipStream_t stream)
{
    const void* target = d_in[0];
    const void* hidden = d_in[1];
    const void* enc    = d_in[2];
    const void* attnW  = d_in[3];
    const void* attnB  = d_in[4];
    const void* combW  = d_in[5];
    const void* combB  = d_in[6];
    const void* Wih    = d_in[7];
    const void* Whh    = d_in[8];
    const void* bih    = d_in[9];
    const void* bhh    = d_in[10];
    const void* out1W  = d_in[11];
    const void* out1B  = d_in[12];
    const void* out2W  = d_in[13];
    const void* out2B  = d_in[14];

    char* ws = (char*)d_ws;
    size_t off = 0;
    #define WSALLOC(name, type, bytes) type* name = (type*)(ws + off); off += (((size_t)(bytes)) + 255) & ~(size_t)255;
    WSALLOC(flag,   int,   256)
    WSALLOC(gi,     float, 256*3072*4)
    WSALLOC(gh,     float, 256*3072*4)
    WSALLOC(xcat,   u16,   256*2048*2)
    WSALLOC(xc,     u16,   256*1024*2)
    WSALLOC(hbv,    u16,   2*256*1024*2)
    WSALLOC(Wc,     u16,   1024*1024*2)
    WSALLOC(attnWB, u16,   96*2048*2)
    WSALLOC(attnBF, float, 128*4)
    WSALLOC(combBF, float, 1024*4)
    WSALLOC(bihF,   float, 2*3072*4)
    WSALLOC(bhhF,   float, 2*3072*4)
    WSALLOC(bc,     float, 1024*4)
    WSALLOC(hf,     float, 2*256*1024*4)
    size_t off_small = off;
    WSALLOC(WihB,   u16,   2*3072*1024*2)
    WSALLOC(WhhB,   u16,   2*3072*1024*2)
    WSALLOC(combWB, u16,   1024*2048*2)
    size_t off_big = off;
    #undef WSALLOC

    const bool BIG   = (ws_size >= off_big);
    const bool useHf = (ws_size >= off_small);
    if (!useHf) hf = nullptr;

    u16* W1t    = BIG ? (u16*)gh : (u16*)gi;  // pre-scan alias, 2 MB
    u16* out2Wb = (u16*)gi;                   // BIG pre-scan alias, 2 MB

    k_detect<<<1, 256, 0, stream>>>((const u32*)target, flag);

    k_init<<<2048, 256, 0, stream>>>(hidden, hf, hbv, flag);
    k_cvt16<<<192, 256, 0, stream>>>(attnW, attnWB, 96*2048/4, flag);
    k_cvtf<<<1, 256, 0, stream>>>(attnB, attnBF, 96, flag);
    k_cvtf<<<4, 256, 0, stream>>>(combB, combBF, 1024, flag);
    k_cvtf<<<24, 256, 0, stream>>>(bih, bihF, 6144, flag);
    k_cvtf<<<24, 256, 0, stream>>>(bhh, bhhF, 6144, flag);
    if (BIG) {
        k_cvt16<<<6144, 256, 0, stream>>>(Wih, WihB, 2*3072*1024/4, flag);
        k_cvt16<<<6144, 256, 0, stream>>>(Whh, WhhB, 2*3072*1024/4, flag);
        k_cvt16<<<2048, 256, 0, stream>>>(combW, combWB, 1024*2048/4, flag);
        k_cvt16<<<1024, 256, 0, stream>>>(out2W, out2Wb, 1024*1024/4, flag);
    }
    k_trcvt<<<dim3(16, 16), 256, 0, stream>>>(out1W, W1t, flag);

    if (BIG) {
        k_gemm<EPI_BF16, 0, 0><<<dim3(16, 8, 1), 128, 0, stream>>>(
            out2Wb, W1t, Wc, out2Wb, W1t, Wc,
            1024, 1024, 1024, 1024, 1024, 0, nullptr, 0, 1024, flag);
    } else {
        k_gemm<EPI_BF16, 1, 0><<<dim3(16, 8, 1), 128, 0, stream>>>(
            out2W, W1t, Wc, out2W, W1t, Wc,
            1024, 1024, 1024, 1024, 1024, 0, nullptr, 0, 1024, flag);
    }
    k_bc<<<4, 256, 0, stream>>>(out2W, out1B, out2B, bc, flag);

    const size_t L1 = 3072ull * 1024ull;
    for (int t = 0; t < T_OUT; ++t) {
        k_attn<<<256, 256, 0, stream>>>(hbv, attnWB, attnBF, enc, target,
                                        xcat, d_out, flag, t);
        if (BIG) {
            k_gemm<EPI_COMB, 0, 0><<<dim3(4, 8, 1), 128, 0, stream>>>(
                xcat, combWB, xc, xcat, combWB, xc,
                2048, 2048, 256, 1024, 2048, 0, combBF, 0, 1024, flag);
            k_gemm<EPI_F32, 0, 0><<<dim3(4, 24, 2), 128, 0, stream>>>(
                xc, WihB, gi, hbv, WhhB, gh,
                1024, 1024, 256, 3072, 1024, 0, nullptr, 0, 3072, flag);
        } else {
            k_gemm<EPI_COMB, 0, 1><<<dim3(4, 8, 1), 128, 0, stream>>>(
                xcat, combW, xc, xcat, combW, xc,
                2048, 2048, 256, 1024, 2048, 0, combBF, 0, 1024, flag);
            k_gemm<EPI_F32, 0, 1><<<dim3(4, 24, 2), 128, 0, stream>>>(
                xc, Wih, gi, hbv, Whh, gh,
                1024, 1024, 256, 3072, 1024, 0, nullptr, 0, 3072, flag);
        }
        k_gate<<<1024, 256, 0, stream>>>(gi, gh, bihF, bhhF, hf, hbv);
        if (BIG) {
            k_gemm<EPI_F32, 0, 0><<<dim3(4, 24, 2), 128, 0, stream>>>(
                hbv, WihB, gi, hbv + 262144, WhhB, gh,
                1024, 1024, 256, 3072, 1024, L1, nullptr, 0, 3072, flag);
        } else {
            k_gemm<EPI_F32, 0, 1><<<dim3(4, 24, 2), 128, 0, stream>>>(
                hbv, Wih, gi, hbv + 262144, Whh, gh,
                1024, 1024, 256, 3072, 1024, L1, nullptr, 0, 3072, flag);
        }
        k_gate<<<1024, 256, 0, stream>>>(gi, gh, bihF + 3072, bhhF + 3072,
                                         hf ? hf + 262144 : nullptr, hbv + 262144);
        k_gemm<EPI_YOUT, 0, 0><<<dim3(4, 8, 1), 128, 0, stream>>>(
            hbv + 262144, Wc, d_out, hbv + 262144, Wc, d_out,
            1024, 1024, 256, 1024, 1024, 0, bc, t, 1024, flag);
    }

    k_hidout<<<2048, 256, 0, stream>>>(hf, hbv, d_out, flag);
}

// Round 5
// 5527.980 us; speedup vs baseline: 1.1147x; 1.1147x over previous
//
#include <hip/hip_runtime.h>
#include <hip/hip_bf16.h>
#include <stdint.h>

typedef unsigned short u16;
typedef unsigned int   u32;
typedef unsigned long long ull;
typedef __attribute__((ext_vector_type(8))) short short8;
typedef __attribute__((ext_vector_type(4))) float f32x4;
typedef __attribute__((ext_vector_type(16))) float f32x16;

#define T_OUT 36
#define NB    256
#define S_IN  96
#define DD    1024
#define HH    1024

#define OFF_HID  9437184
#define OFF_ATTN 9961472

enum { EPI_F32 = 0, EPI_COMB = 1, EPI_BF16 = 2, EPI_YOUT = 3, EPI_YBATCH = 4 };

__device__ __forceinline__ float b2f(u16 u) {
    return __uint_as_float(((u32)u) << 16);
}
__device__ __forceinline__ u16 f2b(float f) {
    __hip_bfloat16 h = __float2bfloat16(f);
    return __builtin_bit_cast(unsigned short, h);
}

template <int RAW>
__device__ __forceinline__ short8 ld8(const void* p, size_t eoff, bool isbf) {
    if (RAW == 0 || isbf) {
        return *(const short8*)((const u16*)p + eoff);
    } else {
        const float* f = (const float*)p + eoff;
        short8 r;
        #pragma unroll
        for (int i = 0; i < 8; ++i) r[i] = (short)f2b(f[i]);
        return r;
    }
}

// dtype detector: flag=1 -> bf16 inputs, 0 -> f32 inputs.
__global__ __launch_bounds__(256) void k_detect(const u32* __restrict__ t,
                                                int* __restrict__ flag)
{
    __shared__ int cnt[256];
    u32 w = t[threadIdx.x];
    int e = (w >> 7) & 0xFF;
    cnt[threadIdx.x] = (e >= 100 && e <= 140) ? 1 : 0;
    __syncthreads();
    for (int s = 128; s > 0; s >>= 1) {
        if (threadIdx.x < s) cnt[threadIdx.x] += cnt[threadIdx.x + s];
        __syncthreads();
    }
    if (threadIdx.x == 0) flag[0] = (cnt[0] >= 128) ? 1 : 0;
}

__global__ __launch_bounds__(256) void k_cvt16(const void* __restrict__ src,
                                               u16* __restrict__ dst, int n4,
                                               const int* __restrict__ flagp)
{
    const int i = blockIdx.x * 256 + threadIdx.x;
    if (i >= n4) return;
    if (*flagp) {
        ((ull*)dst)[i] = ((const ull*)src)[i];
    } else {
        f32x4 v = ((const f32x4*)src)[i];
        ull pk = (ull)f2b(v[0]) | ((ull)f2b(v[1]) << 16)
               | ((ull)f2b(v[2]) << 32) | ((ull)f2b(v[3]) << 48);
        ((ull*)dst)[i] = pk;
    }
}

__global__ __launch_bounds__(256) void k_cvtf(const void* __restrict__ src,
                                              float* __restrict__ dst, int n,
                                              const int* __restrict__ flagp)
{
    const int i = blockIdx.x * 256 + threadIdx.x;
    if (i >= n) return;
    dst[i] = *flagp ? b2f(((const u16*)src)[i]) : ((const float*)src)[i];
}

__global__ __launch_bounds__(256) void k_trcvt(const void* __restrict__ in,
                                               u16* __restrict__ out,
                                               const int* __restrict__ flagp)
{
    const bool isbf = (*flagp != 0);
    __shared__ u16 tile[64][65];
    const int bx = blockIdx.x * 64, by = blockIdx.y * 64;
    const int c = threadIdx.x & 63, r0 = threadIdx.x >> 6;
    #pragma unroll
    for (int rr = 0; rr < 16; ++rr) {
        int r = r0 * 16 + rr;
        size_t idx = (size_t)(by + r) * 1024 + bx + c;
        tile[r][c] = isbf ? ((const u16*)in)[idx] : f2b(((const float*)in)[idx]);
    }
    __syncthreads();
    #pragma unroll
    for (int rr = 0; rr < 16; ++rr) {
        int r = r0 * 16 + rr;
        out[(size_t)(bx + r) * 1024 + by + c] = tile[c][r];
    }
}

__global__ __launch_bounds__(256) void k_bc(const void* __restrict__ W2,
                                            const void* __restrict__ b1,
                                            const void* __restrict__ b2,
                                            float* __restrict__ bc,
                                            const int* __restrict__ flagp)
{
    const bool isbf = (*flagp != 0);
    const int d = blockIdx.x * 256 + threadIdx.x;
    float s = isbf ? b2f(((const u16*)b2)[d]) : ((const float*)b2)[d];
    if (isbf) {
        const u16* wr = (const u16*)W2 + (size_t)d * 1024;
        const u16* bb = (const u16*)b1;
        for (int j = 0; j < 1024; ++j) s += b2f(wr[j]) * b2f(bb[j]);
    } else {
        const float* wr = (const float*)W2 + (size_t)d * 1024;
        const float* bb = (const float*)b1;
        for (int j = 0; j < 1024; ++j) s += wr[j] * bb[j];
    }
    bc[d] = s;
}

// ---------------------------------------------------------------------------
// Generic GEMM (pre/post-scan + comb + per-step yout fallback): 64x128 tile.
// ---------------------------------------------------------------------------
template <int EPI, int RAWA, int RAWB>
__global__ __launch_bounds__(128) void k_gemm(
    const void* __restrict__ A, const void* __restrict__ B, void* __restrict__ Cp,
    int lda, int ldb, int M, int N, int K,
    const float* __restrict__ fbias, int t, int ldc,
    const int* __restrict__ flagp)
{
    const bool isbf = (*flagp != 0);
    __shared__ short8 As[64 * 4];
    __shared__ short8 Bs[128 * 4];

    const int tid  = threadIdx.x;
    const int lane = tid & 63;
    const int w    = tid >> 6;
    const int bm   = blockIdx.x * 64;
    const int bn   = blockIdx.y * 128;

    const int srow = tid >> 2;
    const int sg   = tid & 3;
    const int m0   = lane & 31;
    const int kq   = lane >> 5;

    f32x16 acc[2][2];
    #pragma unroll
    for (int i = 0; i < 2; ++i)
        #pragma unroll
        for (int j = 0; j < 2; ++j) acc[i][j] = (f32x16)0.0f;

    const int kiter = K >> 5;
    for (int kt = 0; kt < kiter; ++kt) {
        const int k0 = kt << 5;
        short8 av[2], bv[4];
        #pragma unroll
        for (int i = 0; i < 2; ++i) {
            int r = srow + 32 * i;
            av[i] = ld8<RAWA>(A, (size_t)(bm + r) * lda + k0 + sg * 8, isbf);
        }
        #pragma unroll
        for (int i = 0; i < 4; ++i) {
            int gr = bn + srow + 32 * i;
            if (gr < N) bv[i] = ld8<RAWB>(B, (size_t)gr * ldb + k0 + sg * 8, isbf);
            else        bv[i] = (short8)(short)0;
        }
        __syncthreads();
        #pragma unroll
        for (int i = 0; i < 2; ++i) {
            int r = srow + 32 * i;
            As[r * 4 + (sg ^ (r & 3))] = av[i];
        }
        #pragma unroll
        for (int i = 0; i < 4; ++i) {
            int r = srow + 32 * i;
            Bs[r * 4 + (sg ^ (r & 3))] = bv[i];
        }
        __syncthreads();
        #pragma unroll
        for (int ks = 0; ks < 2; ++ks) {
            const int gk = ks * 2 + kq;
            short8 af[2], bf[2];
            #pragma unroll
            for (int i = 0; i < 2; ++i) {
                int r = i * 32 + m0;
                af[i] = As[r * 4 + (gk ^ (r & 3))];
            }
            #pragma unroll
            for (int j = 0; j < 2; ++j) {
                int r = w * 64 + j * 32 + m0;
                bf[j] = Bs[r * 4 + (gk ^ (r & 3))];
            }
            #pragma unroll
            for (int i = 0; i < 2; ++i)
                #pragma unroll
                for (int j = 0; j < 2; ++j)
                    acc[i][j] = __builtin_amdgcn_mfma_f32_32x32x16_bf16(
                        af[i], bf[j], acc[i][j], 0, 0, 0);
        }
    }

    #pragma unroll
    for (int i = 0; i < 2; ++i) {
        #pragma unroll
        for (int j = 0; j < 2; ++j) {
            #pragma unroll
            for (int reg = 0; reg < 16; ++reg) {
                int row = (reg & 3) + 8 * (reg >> 2) + 4 * kq;
                int gr = bm + i * 32 + row;
                int gc = bn + w * 64 + j * 32 + m0;
                if (gc < N) {
                    float v = acc[i][j][reg];
                    if constexpr (EPI == EPI_F32) {
                        ((float*)Cp)[(size_t)gr * ldc + gc] = v;
                    } else if constexpr (EPI == EPI_COMB) {
                        v += fbias[gc];
                        v = fmaxf(v, 0.0f);
                        ((u16*)Cp)[(size_t)gr * ldc + gc] = f2b(v);
                    } else if constexpr (EPI == EPI_BF16) {
                        ((u16*)Cp)[(size_t)gr * ldc + gc] = f2b(v);
                    } else if constexpr (EPI == EPI_YOUT) {
                        v += fbias[gc];
                        size_t oidx = (size_t)gr * (T_OUT * DD) + (size_t)t * DD + gc;
                        if (isbf) ((u16*)Cp)[oidx] = f2b(v);
                        else      ((float*)Cp)[oidx] = v;
                    } else { // EPI_YBATCH: gr = t*256+b
                        v += fbias[gc];
                        int tt = gr >> 8, bb = gr & 255;
                        size_t oidx = (size_t)bb * (T_OUT * DD) + (size_t)tt * DD + gc;
                        if (isbf) ((u16*)Cp)[oidx] = f2b(v);
                        else      ((float*)Cp)[oidx] = v;
                    }
                }
            }
        }
    }
}

// ---------------------------------------------------------------------------
// Fused GRU layer: h_new = gate(X@Wih^T, H@Whh^T, h_old), one kernel.
// Tile 64 batch-rows x 32 gate-cols, 6 MFMA accumulator groups.
// Grid (4, 32), 128 threads (2 waves). Hin/Hout MUST be distinct (ping-pong).
// ---------------------------------------------------------------------------
template <int RAWB>
__global__ __launch_bounds__(128) void k_gruf(
    const u16* __restrict__ X, const u16* __restrict__ Hin,
    const void* __restrict__ Wih, const void* __restrict__ Whh, size_t w_eoff,
    const float* __restrict__ biF, const float* __restrict__ bhF,
    float* __restrict__ hfl, u16* __restrict__ Hout,
    u16* __restrict__ hist, int t, const int* __restrict__ flagp)
{
    const bool isbf = (*flagp != 0);
    __shared__ short8 Xs[64 * 4];    // 4 KB
    __shared__ short8 Hs[64 * 4];    // 4 KB
    __shared__ short8 Ws[6 * 32 * 4]; // 12 KB

    const int tid  = threadIdx.x;
    const int lane = tid & 63;
    const int w    = tid >> 6;
    const int bm   = blockIdx.x * 64;     // batch-row tile
    const int J0   = blockIdx.y * 32;     // gate-col tile
    const int m0   = lane & 31;
    const int kq   = lane >> 5;

    f32x16 acc[6];
    #pragma unroll
    for (int g = 0; g < 6; ++g) acc[g] = (f32x16)0.0f;

    const int srr = tid >> 2;   // 0..31
    const int sg  = tid & 3;

    for (int kt = 0; kt < 32; ++kt) {
        const int k0 = kt << 5;
        short8 xv[2], hv[2], wv[6];
        #pragma unroll
        for (int i = 0; i < 2; ++i) {
            int idx = i * 128 + tid;
            int row = idx >> 2, g = idx & 3;
            xv[i] = *(const short8*)(X   + (size_t)(bm + row) * 1024 + k0 + g * 8);
            hv[i] = *(const short8*)(Hin + (size_t)(bm + row) * 1024 + k0 + g * 8);
        }
        #pragma unroll
        for (int i = 0; i < 6; ++i) {
            int gate = (i < 3) ? i : i - 3;
            const void* mat = (i < 3) ? Wih : Whh;
            size_t grow = (size_t)(gate * 1024 + J0 + srr);
            wv[i] = ld8<RAWB>(mat, w_eoff + grow * 1024 + k0 + sg * 8, isbf);
        }
        __syncthreads();
        #pragma unroll
        for (int i = 0; i < 2; ++i) {
            int idx = i * 128 + tid;
            int row = idx >> 2, g = idx & 3;
            Xs[row * 4 + (g ^ (row & 3))] = xv[i];
            Hs[row * 4 + (g ^ (row & 3))] = hv[i];
        }
        #pragma unroll
        for (int i = 0; i < 6; ++i) {
            Ws[(i * 32 + srr) * 4 + (sg ^ (srr & 3))] = wv[i];
        }
        __syncthreads();
        #pragma unroll
        for (int ks = 0; ks < 2; ++ks) {
            const int gk = ks * 2 + kq;
            const int r = w * 32 + m0;
            short8 ax = Xs[r * 4 + (gk ^ (r & 3))];
            short8 ah = Hs[r * 4 + (gk ^ (r & 3))];
            short8 bw[6];
            #pragma unroll
            for (int g = 0; g < 6; ++g)
                bw[g] = Ws[(g * 32 + m0) * 4 + (gk ^ (m0 & 3))];
            acc[0] = __builtin_amdgcn_mfma_f32_32x32x16_bf16(ax, bw[0], acc[0], 0, 0, 0);
            acc[1] = __builtin_amdgcn_mfma_f32_32x32x16_bf16(ax, bw[1], acc[1], 0, 0, 0);
            acc[2] = __builtin_amdgcn_mfma_f32_32x32x16_bf16(ax, bw[2], acc[2], 0, 0, 0);
            acc[3] = __builtin_amdgcn_mfma_f32_32x32x16_bf16(ah, bw[3], acc[3], 0, 0, 0);
            acc[4] = __builtin_amdgcn_mfma_f32_32x32x16_bf16(ah, bw[4], acc[4], 0, 0, 0);
            acc[5] = __builtin_amdgcn_mfma_f32_32x32x16_bf16(ah, bw[5], acc[5], 0, 0, 0);
        }
        __syncthreads();
    }

    // epilogue: col=lane&31 -> j, row=(reg&3)+8*(reg>>2)+4*kq -> batch row
    const int jg = J0 + m0;
    const float bir = biF[jg],        bhr = bhF[jg];
    const float biz = biF[1024 + jg], bhz = bhF[1024 + jg];
    const float bin_ = biF[2048 + jg], bhn = bhF[2048 + jg];
    #pragma unroll
    for (int reg = 0; reg < 16; ++reg) {
        int row = (reg & 3) + 8 * (reg >> 2) + 4 * kq;
        int bb = bm + w * 32 + row;
        float ir  = acc[0][reg] + bir;
        float iz  = acc[1][reg] + biz;
        float in_ = acc[2][reg] + bin_;
        float hr  = acc[3][reg] + bhr;
        float hz  = acc[4][reg] + bhz;
        float hn  = acc[5][reg] + bhn;
        float r = 1.f / (1.f + expf(-(ir + hr)));
        float z = 1.f / (1.f + expf(-(iz + hz)));
        float n = tanhf(in_ + r * hn);
        size_t hidx = (size_t)bb * 1024 + jg;
        float hold = hfl ? hfl[hidx] : b2f(Hin[hidx]);
        float hnew = (1.f - z) * n + z * hold;
        if (hfl) hfl[hidx] = hnew;
        u16 h16 = f2b(hnew);
        Hout[hidx] = h16;
        if (hist) hist[(size_t)(t * NB + bb) * HH + jg] = h16;
    }
}

// ---------------------------------------------------------------------------
// Fused attention step: scores (wave-parallel dots) + softmax + weighted enc
// sum; assembles xcat[b] = [x_t | w_enc]. One block per batch element.
// ---------------------------------------------------------------------------
__global__ __launch_bounds__(256) void k_attn(
    const u16* __restrict__ hb1, const u16* __restrict__ attnWB,
    const float* __restrict__ attnBF, const void* __restrict__ enc,
    const void* __restrict__ target, u16* __restrict__ xcat,
    void* __restrict__ d_out, const int* __restrict__ flagp, int t)
{
    const bool isbf = (*flagp != 0);
    __shared__ float cbuf[2048];
    __shared__ float sc[S_IN];
    __shared__ float red[2];
    const int b = blockIdx.x, tid = threadIdx.x;
    const int lane = tid & 63, w = tid >> 6;

    float x0, x1, x2, x3;
    const size_t xoff = ((size_t)b * T_OUT + t) * DD + (size_t)tid * 4;
    if (isbf) {
        ull xv = *(const ull*)((const u16*)target + xoff);
        x0 = b2f((u16)(xv & 0xffff));
        x1 = b2f((u16)((xv >> 16) & 0xffff));
        x2 = b2f((u16)((xv >> 32) & 0xffff));
        x3 = b2f((u16)(xv >> 48));
    } else {
        f32x4 v = *(const f32x4*)((const float*)target + xoff);
        x0 = v[0]; x1 = v[1]; x2 = v[2]; x3 = v[3];
    }
    cbuf[tid * 4 + 0] = x0; cbuf[tid * 4 + 1] = x1;
    cbuf[tid * 4 + 2] = x2; cbuf[tid * 4 + 3] = x3;
    ull pk = (ull)f2b(x0) | ((ull)f2b(x1) << 16)
           | ((ull)f2b(x2) << 32) | ((ull)f2b(x3) << 48);
    ((ull*)(xcat + (size_t)b * 2048))[tid] = pk;

    ull hv = ((const ull*)(hb1 + (size_t)b * HH))[tid];
    cbuf[1024 + tid * 4 + 0] = b2f((u16)(hv & 0xffff));
    cbuf[1024 + tid * 4 + 1] = b2f((u16)((hv >> 16) & 0xffff));
    cbuf[1024 + tid * 4 + 2] = b2f((u16)((hv >> 32) & 0xffff));
    cbuf[1024 + tid * 4 + 3] = b2f((u16)(hv >> 48));
    __syncthreads();

    // scores: 4 waves x 24 scores, 64-lane dot + shuffle reduce
    for (int i = 0; i < 24; ++i) {
        int s = w * 24 + i;
        const u16* wr = attnWB + (size_t)s * 2048;
        float p = 0.f;
        #pragma unroll
        for (int c = 0; c < 4; ++c) {
            short8 v = *(const short8*)(wr + c * 512 + lane * 8);
            const float* cb = cbuf + c * 512 + lane * 8;
            #pragma unroll
            for (int e = 0; e < 8; ++e) p += cb[e] * b2f((u16)v[e]);
        }
        #pragma unroll
        for (int d = 32; d > 0; d >>= 1) p += __shfl_xor(p, d, 64);
        if (lane == 0) sc[s] = p + attnBF[s];
    }
    __syncthreads();
    if (tid == 0) {
        float m = -1e30f;
        for (int s = 0; s < S_IN; ++s) m = fmaxf(m, sc[s]);
        red[0] = m;
    }
    __syncthreads();
    if (tid < S_IN) sc[tid] = expf(sc[tid] - red[0]);
    __syncthreads();
    if (tid == 0) {
        float s = 0.f;
        for (int i = 0; i < S_IN; ++i) s += sc[i];
        red[1] = 1.0f / s;
    }
    __syncthreads();
    if (tid < S_IN) {
        float a = sc[tid] * red[1];
        sc[tid] = a;
        size_t aidx = OFF_ATTN + (size_t)b * T_OUT * S_IN + (size_t)t * S_IN + tid;
        if (isbf) ((u16*)d_out)[aidx] = f2b(a);
        else      ((float*)d_out)[aidx] = a;
    }
    __syncthreads();

    float a0 = 0.f, a1 = 0.f, a2 = 0.f, a3 = 0.f;
    if (isbf) {
        const u16* eb = (const u16*)enc + (size_t)b * S_IN * HH + (size_t)tid * 4;
        for (int s = 0; s < S_IN; ++s) {
            float aw = sc[s];
            ull v = *(const ull*)(eb + (size_t)s * HH);
            a0 += aw * b2f((u16)(v & 0xffff));
            a1 += aw * b2f((u16)((v >> 16) & 0xffff));
            a2 += aw * b2f((u16)((v >> 32) & 0xffff));
            a3 += aw * b2f((u16)(v >> 48));
        }
    } else {
        const float* eb = (const float*)enc + (size_t)b * S_IN * HH + (size_t)tid * 4;
        for (int s = 0; s < S_IN; ++s) {
            float aw = sc[s];
            f32x4 v = *(const f32x4*)(eb + (size_t)s * HH);
            a0 += aw * v[0]; a1 += aw * v[1]; a2 += aw * v[2]; a3 += aw * v[3];
        }
    }
    ull wk = (ull)f2b(a0) | ((ull)f2b(a1) << 16)
           | ((ull)f2b(a2) << 32) | ((ull)f2b(a3) << 48);
    *(ull*)(xcat + (size_t)b * 2048 + 1024 + (size_t)tid * 4) = wk;
}

__global__ __launch_bounds__(256) void k_init(const void* __restrict__ hid,
                                              float* __restrict__ hf,
                                              u16* __restrict__ hb,
                                              const int* __restrict__ flagp)
{
    const int i = blockIdx.x * 256 + threadIdx.x;
    float v = *flagp ? b2f(((const u16*)hid)[i]) : ((const float*)hid)[i];
    if (hf) hf[i] = v;
    hb[i] = f2b(v);
}

__global__ __launch_bounds__(256) void k_hidout(const float* __restrict__ hf,
                                                const u16* __restrict__ hb,
                                                void* __restrict__ d_out,
                                                const int* __restrict__ flagp)
{
    const int i = blockIdx.x * 256 + threadIdx.x;
    float v = hf ? hf[i] : b2f(hb[i]);
    if (*flagp) ((u16*)d_out)[OFF_HID + i] = f2b(v);
    else        ((float*)d_out)[OFF_HID + i] = v;
}

// ---------------------------------------------------------------------------
extern "C" void kernel_launch(void* const* d_in, const int* in_sizes, int n_in,
                              void* d_out, int out_size, void* d_ws, size_t ws_size,
                              hipStream_t stream)
{
    const void* target = d_in[0];
    const void* hidden = d_in[1];
    const void* enc    = d_in[2];
    const void* attnW  = d_in[3];
    const void* attnB  = d_in[4];
    const void* combW  = d_in[5];
    const void* combB  = d_in[6];
    const void* Wih    = d_in[7];
    const void* Whh    = d_in[8];
    const void* bih    = d_in[9];
    const void* bhh    = d_in[10];
    const void* out1W  = d_in[11];
    const void* out1B  = d_in[12];
    const void* out2W  = d_in[13];
    const void* out2B  = d_in[14];

    char* ws = (char*)d_ws;
    size_t off = 0;
    #define WSALLOC(name, type, bytes) type* name = (type*)(ws + off); off += (((size_t)(bytes)) + 255) & ~(size_t)255;
    WSALLOC(flag,   int,   256)
    WSALLOC(xcat,   u16,   256*2048*2)        // 1 MB
    WSALLOC(xc,     u16,   256*1024*2)        // 0.5 MB
    WSALLOC(hbq,    u16,   2*2*256*1024*2)    // 2 MB  (ping-pong x 2 layers)
    WSALLOC(Wc,     u16,   1024*1024*2)       // 2 MB
    WSALLOC(attnWB, u16,   96*2048*2)         // 384 KB
    WSALLOC(attnBF, float, 128*4)
    WSALLOC(combBF, float, 1024*4)
    WSALLOC(bihF,   float, 2*3072*4)
    WSALLOC(bhhF,   float, 2*3072*4)
    WSALLOC(bc,     float, 1024*4)
    WSALLOC(W1t,    u16,   1024*1024*2)       // 2 MB
    size_t off_nohf = off;
    WSALLOC(hf,     float, 2*256*1024*4)      // 2 MB
    size_t off_core = off;                    // ~10.6 MB
    WSALLOC(WihB,   u16,   2*3072*1024*2)     // 12.6 MB
    WSALLOC(WhhB,   u16,   2*3072*1024*2)     // 12.6 MB
    WSALLOC(combWB, u16,   1024*2048*2)       // 4.2 MB
    size_t off_big = off;                     // ~40 MB
    WSALLOC(Hist,   u16,   36*256*1024*2)     // 18.9 MB
    size_t off_hist = off;                    // ~59 MB
    #undef WSALLOC
    (void)off_nohf;

    const bool useHf   = (ws_size >= off_core);
    const bool BIG     = (ws_size >= off_big);
    const bool useHist = (ws_size >= off_hist);
    if (!useHf) hf = nullptr;

    k_detect<<<1, 256, 0, stream>>>((const u32*)target, flag);

    k_init<<<2048, 256, 0, stream>>>(hidden, hf, hbq, flag);   // buf0
    k_cvt16<<<192, 256, 0, stream>>>(attnW, attnWB, 96*2048/4, flag);
    k_cvtf<<<1, 256, 0, stream>>>(attnB, attnBF, 96, flag);
    k_cvtf<<<4, 256, 0, stream>>>(combB, combBF, 1024, flag);
    k_cvtf<<<24, 256, 0, stream>>>(bih, bihF, 6144, flag);
    k_cvtf<<<24, 256, 0, stream>>>(bhh, bhhF, 6144, flag);
    k_trcvt<<<dim3(16, 16), 256, 0, stream>>>(out1W, W1t, flag);

    // Wc = out2W @ out1W ; bc = out2W @ b1 + b2
    if (BIG) {
        u16* out2Wb = WihB;   // temp alias, converted before WihB is filled
        k_cvt16<<<1024, 256, 0, stream>>>(out2W, out2Wb, 1024*1024/4, flag);
        k_gemm<EPI_BF16, 0, 0><<<dim3(16, 8, 1), 128, 0, stream>>>(
            out2Wb, W1t, Wc, 1024, 1024, 1024, 1024, 1024, nullptr, 0, 1024, flag);
        k_cvt16<<<6144, 256, 0, stream>>>(Wih, WihB, 2*3072*1024/4, flag);
        k_cvt16<<<6144, 256, 0, stream>>>(Whh, WhhB, 2*3072*1024/4, flag);
        k_cvt16<<<2048, 256, 0, stream>>>(combW, combWB, 1024*2048/4, flag);
    } else {
        k_gemm<EPI_BF16, 1, 0><<<dim3(16, 8, 1), 128, 0, stream>>>(
            out2W, W1t, Wc, 1024, 1024, 1024, 1024, 1024, nullptr, 0, 1024, flag);
    }
    k_bc<<<4, 256, 0, stream>>>(out2W, out1B, out2B, bc, flag);

    const size_t L1 = 3072ull * 1024ull;   // layer-1 element offset
    const int BUF = 2 * 256 * 1024;        // ping-pong buffer stride (elems)
    for (int t = 0; t < T_OUT; ++t) {
        u16* bi = hbq + (t & 1) * BUF;          // h state in
        u16* bo = hbq + ((t + 1) & 1) * BUF;    // h state out
        k_attn<<<256, 256, 0, stream>>>(bi + 262144, attnWB, attnBF, enc, target,
                                        xcat, d_out, flag, t);
        if (BIG) {
            k_gemm<EPI_COMB, 0, 0><<<dim3(4, 8, 1), 128, 0, stream>>>(
                xcat, combWB, xc, 2048, 2048, 256, 1024, 2048, combBF, 0, 1024, flag);
            k_gruf<0><<<dim3(4, 32), 128, 0, stream>>>(
                xc, bi, WihB, WhhB, 0, bihF, bhhF, hf, bo, nullptr, t, flag);
            k_gruf<0><<<dim3(4, 32), 128, 0, stream>>>(
                bo, bi + 262144, WihB, WhhB, L1, bihF + 3072, bhhF + 3072,
                hf ? hf + 262144 : nullptr, bo + 262144,
                useHist ? Hist : nullptr, t, flag);
        } else {
            k_gemm<EPI_COMB, 0, 1><<<dim3(4, 8, 1), 128, 0, stream>>>(
                xcat, combW, xc, 2048, 2048, 256, 1024, 2048, combBF, 0, 1024, flag);
            k_gruf<1><<<dim3(4, 32), 128, 0, stream>>>(
                xc, bi, Wih, Whh, 0, bihF, bhhF, hf, bo, nullptr, t, flag);
            k_gruf<1><<<dim3(4, 32), 128, 0, stream>>>(
                bo, bi + 262144, Wih, Whh, L1, bihF + 3072, bhhF + 3072,
                hf ? hf + 262144 : nullptr, bo + 262144,
                useHist ? Hist : nullptr, t, flag);
        }
        if (!useHist) {
            k_gemm<EPI_YOUT, 0, 0><<<dim3(4, 8, 1), 128, 0, stream>>>(
                bo + 262144, Wc, d_out, 1024, 1024, 256, 1024, 1024, bc, t, 1024, flag);
        }
    }

    if (useHist) {
        // batched y = Hist @ Wc^T + bc over all 36 steps (M = 9216)
        k_gemm<EPI_YBATCH, 0, 0><<<dim3(144, 8, 1), 128, 0, stream>>>(
            Hist, Wc, d_out, 1024, 1024, 9216, 1024, 1024, bc, 0, 1024, flag);
    }
    // final hidden: after 36 steps state is in buf (36&1)=0
    k_hidout<<<2048, 256, 0, stream>>>(hf, hbq, d_out, flag);
}